// Round 6
// baseline (115.172 us; speedup 1.0000x reference)
//
#include <hip/hip_runtime.h>
#include <math.h>

#define NN 512
#define MM (NN * NN)
#define HW (NN * NN)
#define CH 3

__device__ __forceinline__ float dct_s(int k) {
    // s_0 = sqrt(1/512), s_k = sqrt(2/512)
    return (k == 0) ? 0.04419417382415922f : 0.0625f;
}

// ---------------- Stage A: T[h][wp] ----------------
// Tr[h][wp] = sum_hp D[hp][h]*att[hp][wp]*rw[hp]
// Tc[h][wp] = cw[wp] * sum_hp D[hp][h]*att[hp][wp]
// 1024 blocks = 128 h-groups(4h) x 8 wp-eighths(64wp). 256 thr = 4 k-chunks x 64 lanes.
__global__ void __launch_bounds__(256) k_stageA(
    const float* __restrict__ att, const float* __restrict__ rw,
    const float* __restrict__ cw, float* __restrict__ Tr, float* __restrict__ Tc,
    unsigned int* __restrict__ counter)
{
    __shared__ float sD[2048];        // [hp][i] = D[hp][h0+i], computed in-kernel
    __shared__ float sRw[512];
    __shared__ float sAcc[256 * 9];   // pad 9 -> conflict-free k-reduction
    const int tid = threadIdx.x;
    const int bx  = blockIdx.x;
    if (bx == 0 && tid == 0) *counter = 0u;   // reset for fused reduce+final
    const int h0  = (bx >> 3) * 4;
    const int wp0 = (bx & 7) * 64;
    const int kc  = tid >> 6;
    const int wl  = tid & 63;
    const int wp  = wp0 + wl;
    const int hp0 = kc * 128;

    #pragma unroll
    for (int e = 0; e < 8; ++e) {                 // 2048 D entries, 8/thread
        int idx = tid * 8 + e;
        int hp = idx >> 2, i = idx & 3;
        int m = ((2 * (h0 + i) + 1) * hp) & 2047; // exact mod 4N
        sD[idx] = dct_s(hp) * cospif((float)m * (1.0f / 1024.0f));
    }
    sRw[tid] = rw[tid];
    sRw[256 + tid] = rw[256 + tid];
    __syncthreads();

    float ar0=0.f,ar1=0.f,ar2=0.f,ar3=0.f, as0=0.f,as1=0.f,as2=0.f,as3=0.f;
    #pragma unroll 4
    for (int t = 0; t < 128; ++t) {
        int hp = hp0 + t;
        float a = att[hp * NN + wp];              // coalesced 256B/wave
        float r = sRw[hp];                        // LDS broadcast
        float4 d = *reinterpret_cast<const float4*>(&sD[hp * 4]); // broadcast
        float ra = r * a;
        ar0 += d.x * ra; as0 += d.x * a;
        ar1 += d.y * ra; as1 += d.y * a;
        ar2 += d.z * ra; as2 += d.z * a;
        ar3 += d.w * ra; as3 += d.w * a;
    }
    float* sa = &sAcc[tid * 9];
    sa[0]=ar0; sa[1]=ar1; sa[2]=ar2; sa[3]=ar3;
    sa[4]=as0; sa[5]=as1; sa[6]=as2; sa[7]=as3;
    __syncthreads();
    if (tid < 64) {
        float v[8];
        #pragma unroll
        for (int j = 0; j < 8; ++j)
            v[j] = sAcc[(0*64 + tid)*9 + j] + sAcc[(1*64 + tid)*9 + j]
                 + sAcc[(2*64 + tid)*9 + j] + sAcc[(3*64 + tid)*9 + j];
        float c = cw[wp0 + tid];
        #pragma unroll
        for (int i = 0; i < 4; ++i) {
            Tr[(h0 + i) * NN + wp0 + tid] = v[i];
            Tc[(h0 + i) * NN + wp0 + tid] = v[4 + i] * c;
        }
    }
}

// ---------------- Stage B: G[h][w] = sum_wp T[h][wp] * D[wp][w] ----------------
__global__ void __launch_bounds__(256) k_stageB(
    const float* __restrict__ Tr, const float* __restrict__ Tc,
    float* __restrict__ Gr, float* __restrict__ Gc)
{
    __shared__ float sT[512 * 8];     // [wp][0..3]=Tr(h0..h0+3), [4..7]=Tc
    __shared__ float sAcc[256 * 9];
    const int tid = threadIdx.x;
    const int bx  = blockIdx.x;
    const int h0  = (bx >> 3) * 4;
    const int w0  = (bx & 7) * 64;
    const int kc  = tid >> 6;
    const int wl  = tid & 63;
    const int w   = w0 + wl;
    const int wp0 = kc * 128;

    #pragma unroll
    for (int i = 0; i < 4; ++i) {                 // coalesced global reads
        sT[tid * 8 + i]             = Tr[(h0 + i) * NN + tid];
        sT[tid * 8 + 4 + i]         = Tc[(h0 + i) * NN + tid];
        sT[(tid + 256) * 8 + i]     = Tr[(h0 + i) * NN + tid + 256];
        sT[(tid + 256) * 8 + 4 + i] = Tc[(h0 + i) * NN + tid + 256];
    }
    __syncthreads();

    float gr0=0.f,gr1=0.f,gr2=0.f,gr3=0.f, gc0=0.f,gc1=0.f,gc2=0.f,gc3=0.f;
    const int w2 = 2 * w + 1;
    int m = (w2 * wp0) & 2047;                    // incremental phase
    #pragma unroll 4
    for (int t = 0; t < 128; ++t) {
        int wp = wp0 + t;
        float s = (wp == 0) ? 0.04419417382415922f : 0.0625f;
        float d = s * cospif((float)m * (1.0f / 1024.0f));
        m = (m + w2) & 2047;
        float4 ta = *reinterpret_cast<const float4*>(&sT[wp * 8]);     // broadcast
        float4 tb = *reinterpret_cast<const float4*>(&sT[wp * 8 + 4]); // broadcast
        gr0 += ta.x * d; gr1 += ta.y * d; gr2 += ta.z * d; gr3 += ta.w * d;
        gc0 += tb.x * d; gc1 += tb.y * d; gc2 += tb.z * d; gc3 += tb.w * d;
    }
    float* sa = &sAcc[tid * 9];
    sa[0]=gr0; sa[1]=gr1; sa[2]=gr2; sa[3]=gr3;
    sa[4]=gc0; sa[5]=gc1; sa[6]=gc2; sa[7]=gc3;
    __syncthreads();
    if (tid < 64) {
        float v[8];
        #pragma unroll
        for (int j = 0; j < 8; ++j)
            v[j] = sAcc[(0*64 + tid)*9 + j] + sAcc[(1*64 + tid)*9 + j]
                 + sAcc[(2*64 + tid)*9 + j] + sAcc[(3*64 + tid)*9 + j];
        #pragma unroll
        for (int i = 0; i < 4; ++i) {
            Gr[(h0 + i) * NN + w0 + tid] = v[i];
            Gc[(h0 + i) * NN + w0 + tid] = v[4 + i];
        }
    }
}

// ---------------- Reduce + final (fused): ----------------
// grid (32, 32): ck chunk x batch-group; each block handles b and b+32 sharing G loads.
// Last finishing block performs the final 32-way sums + sigmoid (fixed order ->
// deterministic regardless of which block is last).
__global__ void __launch_bounds__(256) k_reduce_final(
    const float* __restrict__ x, const float* __restrict__ Gr,
    const float* __restrict__ Gc, float* __restrict__ partials,
    unsigned int* __restrict__ counter, float* __restrict__ out)
{
    const int ck = blockIdx.x;       // 0..31
    const int b1 = blockIdx.y;       // 0..31
    const int b2 = b1 + 32;
    const int t  = threadIdx.x;
    const float* xb1 = x + (size_t)b1 * (CH * HW);
    const float* xb2 = x + (size_t)b2 * (CH * HW);
    const int hw0 = ck * (HW / 32);  // 8192-wide chunk

    float ar1 = 0.f, ac1 = 0.f, ar2 = 0.f, ac2 = 0.f;
    #pragma unroll 2
    for (int j = 0; j < 8; ++j) {
        int hw = hw0 + j * 1024 + t * 4;
        float4 gr = *(const float4*)(Gr + hw);
        float4 gc = *(const float4*)(Gc + hw);
        float4 p0 = *(const float4*)(xb1 + hw);
        float4 p1 = *(const float4*)(xb1 + HW + hw);
        float4 p2 = *(const float4*)(xb1 + 2 * HW + hw);
        float4 q0 = *(const float4*)(xb2 + hw);
        float4 q1 = *(const float4*)(xb2 + HW + hw);
        float4 q2 = *(const float4*)(xb2 + 2 * HW + hw);
        float s1x = p0.x + p1.x + p2.x, s1y = p0.y + p1.y + p2.y;
        float s1z = p0.z + p1.z + p2.z, s1w = p0.w + p1.w + p2.w;
        float s2x = q0.x + q1.x + q2.x, s2y = q0.y + q1.y + q2.y;
        float s2z = q0.z + q1.z + q2.z, s2w = q0.w + q1.w + q2.w;
        ar1 += gr.x * s1x + gr.y * s1y + gr.z * s1z + gr.w * s1w;
        ac1 += gc.x * s1x + gc.y * s1y + gc.z * s1z + gc.w * s1w;
        ar2 += gr.x * s2x + gr.y * s2y + gr.z * s2z + gr.w * s2w;
        ac2 += gc.x * s2x + gc.y * s2y + gc.z * s2z + gc.w * s2w;
    }
    for (int off = 32; off > 0; off >>= 1) {
        ar1 += __shfl_down(ar1, off);
        ac1 += __shfl_down(ac1, off);
        ar2 += __shfl_down(ar2, off);
        ac2 += __shfl_down(ac2, off);
    }
    __shared__ float sm[4][4];
    __shared__ bool sdone;
    int wid = t >> 6;
    if ((t & 63) == 0) {
        sm[wid][0] = ar1; sm[wid][1] = ac1; sm[wid][2] = ar2; sm[wid][3] = ac2;
    }
    __syncthreads();
    if (t == 0) {
        float r1 = sm[0][0] + sm[1][0] + sm[2][0] + sm[3][0];
        float c1 = sm[0][1] + sm[1][1] + sm[2][1] + sm[3][1];
        float r2 = sm[0][2] + sm[1][2] + sm[2][2] + sm[3][2];
        float c2 = sm[0][3] + sm[1][3] + sm[2][3] + sm[3][3];
        partials[(b1 * 32 + ck) * 2 + 0] = r1;
        partials[(b1 * 32 + ck) * 2 + 1] = c1;
        partials[(b2 * 32 + ck) * 2 + 0] = r2;
        partials[(b2 * 32 + ck) * 2 + 1] = c2;
        __threadfence();
        unsigned int old = atomicAdd(counter, 1u);
        sdone = (old == 32u * 32u - 1u);
    }
    __syncthreads();
    if (sdone) {
        __threadfence();                 // acquire all partials
        if (t < 64) {
            float r = 0.f, c = 0.f;
            #pragma unroll
            for (int i = 0; i < 32; ++i) {
                r += partials[(t * 32 + i) * 2 + 0];
                c += partials[(t * 32 + i) * 2 + 1];
            }
            const float inv = 1.0f / (float)(CH * HW);
            r *= inv; c *= inv;
            out[t * 2 + 0] = 1.0f / (1.0f + expf(-c));   // col_out first
            out[t * 2 + 1] = 1.0f / (1.0f + expf(-r));
        }
        if (t == 0) *counter = 0u;       // self-reset for next replay
    }
}

extern "C" void kernel_launch(void* const* d_in, const int* in_sizes, int n_in,
                              void* d_out, int out_size, void* d_ws, size_t ws_size,
                              hipStream_t stream) {
    const float* x   = (const float*)d_in[0];   // [64,3,512,512]
    const float* att = (const float*)d_in[1];   // [512,512]
    const float* rw  = (const float*)d_in[2];   // [512]
    const float* cw  = (const float*)d_in[3];   // [512]
    float* out = (float*)d_out;                 // [64,2]

    float* ws = (float*)d_ws;
    float* Tr = ws;
    float* Tc = ws + 1 * MM;
    float* Gr = ws + 2 * MM;
    float* Gc = ws + 3 * MM;
    float* partials = ws + 4 * MM;              // 64*32*2 = 4096
    unsigned int* counter = (unsigned int*)(ws + 4 * MM + 4096);

    k_stageA<<<1024, 256, 0, stream>>>(att, rw, cw, Tr, Tc, counter);
    k_stageB<<<1024, 256, 0, stream>>>(Tr, Tc, Gr, Gc);
    dim3 g(32, 32);
    k_reduce_final<<<g, 256, 0, stream>>>(x, Gr, Gc, partials, counter, out);
}